// Round 11
// baseline (484.693 us; speedup 1.0000x reference)
//
#include <hip/hip_runtime.h>
#include <hip/hip_bf16.h>

// TokenRoutedMLP: N=32768 tokens, H=1024, 8 routed experts (id%8) + shared expert.
// Grouped bf16 MFMA GEMMs; shared expert folded via concat weights; gate/up
// interleaved by 16 cols in W1 so silu pairing is in-register.
// GEMM: R6 multi-block-overlap regime (128x128 tile, BK=32, 4 waves, ~3 blocks/CU)
// + T4 counted vmcnt: ring-3 LDS (48 KB), raw s_barrier, vmcnt(8) steady state
// (loads span 2 iterations; never drained to 0 until tail). Fragment-ordered LDS
// (verified 0-conflict, R7): frag f at f*1024B + lane*16B.
// global_load_lds: LDS dest wave-uniform base + lane*16B (m104/m108).

#define N_TOK 32768
#define HD 1024
#define NE 8

typedef __attribute__((ext_vector_type(8))) short bf16x8;
typedef __attribute__((ext_vector_type(8))) unsigned short u16x8;
typedef __attribute__((ext_vector_type(4))) float f32x4;

#define BAR() asm volatile("s_barrier" ::: "memory")

__device__ __forceinline__ unsigned short f2bf(float f) {
  unsigned int x = __float_as_uint(f);
  x += 0x7fffu + ((x >> 16) & 1u);   // RTNE
  return (unsigned short)(x >> 16);
}

__device__ __forceinline__ void gld16(const unsigned short* g, unsigned short* l) {
  __builtin_amdgcn_global_load_lds(
      (const __attribute__((address_space(1))) unsigned int*)g,
      (__attribute__((address_space(3))) unsigned int*)l,
      16, 0, 0);
}

__device__ __forceinline__ int expert_of(int id) {
  int v = id < 0 ? 0 : (id > 99999 ? 99999 : id);
  return v & 7;
}

// ---------------- routing (LDS-histogram; 8 global atomics per block) ----------
__global__ void k_zero(int* ctrl) {
  if (threadIdx.x < 16) ctrl[threadIdx.x] = 0;   // cnt[8], cursor[8]
}

__global__ void k_count(const int* __restrict__ ids, int* __restrict__ cnt) {
  __shared__ int l[NE];
  if (threadIdx.x < NE) l[threadIdx.x] = 0;
  __syncthreads();
  int t = blockIdx.x * 256 + threadIdx.x;
  atomicAdd(&l[expert_of(ids[t])], 1);
  __syncthreads();
  if (threadIdx.x < NE) atomicAdd(&cnt[threadIdx.x], l[threadIdx.x]);
}

__global__ void k_scan(const int* __restrict__ cnt, int* __restrict__ off) {
  if (threadIdx.x == 0 && blockIdx.x == 0) {
    int a = 0;
    for (int e = 0; e < NE; e++) { off[e] = a; a += (cnt[e] + 127) & ~127; }
    off[NE] = a;
  }
}

__global__ void k_fill(const int* __restrict__ ids, int* __restrict__ cursor,
                       const int* __restrict__ off, int* __restrict__ perm) {
  __shared__ int lcnt[NE], lbase[NE];
  if (threadIdx.x < NE) lcnt[threadIdx.x] = 0;
  __syncthreads();
  int t = blockIdx.x * 256 + threadIdx.x;
  int e = expert_of(ids[t]);
  int r = atomicAdd(&lcnt[e], 1);          // rank within block
  __syncthreads();
  if (threadIdx.x < NE)
    lbase[threadIdx.x] = atomicAdd(&cursor[threadIdx.x], lcnt[threadIdx.x]);
  __syncthreads();
  perm[off[e] + lbase[e] + r] = t;
}

// ---------------- conversions / weight build ----------------
__global__ void k_cvt_x(const float* __restrict__ src, unsigned short* __restrict__ dst) {
  size_t i = ((size_t)blockIdx.x * 256 + threadIdx.x) * 8;
  float4 a = *reinterpret_cast<const float4*>(src + i);
  float4 b = *reinterpret_cast<const float4*>(src + i + 4);
  u16x8 o;
  o[0]=f2bf(a.x); o[1]=f2bf(a.y); o[2]=f2bf(a.z); o[3]=f2bf(a.w);
  o[4]=f2bf(b.x); o[5]=f2bf(b.y); o[6]=f2bf(b.z); o[7]=f2bf(b.w);
  *reinterpret_cast<u16x8*>(dst + i) = o;
}

// row remap: mode 0 plain; mode 1 gate-interleave; mode 2 up-interleave
__device__ __forceinline__ int rowmap(int c, int mode) {
  if (mode == 0) return c;
  return ((c >> 4) << 5) + (c & 15) + (mode == 2 ? 16 : 0);
}

// transpose-convert: src f32 [R][C] per expert -> dst bf16 [rowmap(col)][src_row], stride HD
__global__ void k_transpose_cvt(const float* __restrict__ src0, unsigned short* __restrict__ dst0,
                                int C, int mode, size_t src_estride, size_t dst_estride) {
  const float* src = src0 + blockIdx.z * src_estride;
  unsigned short* dst = dst0 + blockIdx.z * dst_estride;
  __shared__ __attribute__((aligned(16))) float tile[32][33];
  int t = threadIdx.x;
  int r0 = blockIdx.y * 32, c0 = blockIdx.x * 32;
  int row = t >> 3, c4 = (t & 7) * 4;
  float4 v = *reinterpret_cast<const float4*>(src + (size_t)(r0 + row) * C + c0 + c4);
  tile[row][c4+0] = v.x; tile[row][c4+1] = v.y; tile[row][c4+2] = v.z; tile[row][c4+3] = v.w;
  __syncthreads();
  ushort4 o;
  o.x = f2bf(tile[c4+0][row]); o.y = f2bf(tile[c4+1][row]);
  o.z = f2bf(tile[c4+2][row]); o.w = f2bf(tile[c4+3][row]);
  int orow = rowmap(c0 + row, mode);
  *reinterpret_cast<ushort4*>(dst + (size_t)orow * HD + r0 + c4) = o;
}

// copy-convert: src f32 [rows][cols] -> dst row (1024+rowmap(r) if mode, else r), col dcol+c
__global__ void k_copy_cvt(const float* __restrict__ src, unsigned short* __restrict__ dst,
                           int cols, int mode, int dcol, size_t dst_estride) {
  size_t i = ((size_t)blockIdx.x * 256 + threadIdx.x) * 4;
  int r = (int)(i / cols), c = (int)(i % cols);
  int row = (mode == 0) ? r : (1024 + rowmap(r, mode));
  float4 v = *reinterpret_cast<const float4*>(src + i);
  ushort4 o; o.x=f2bf(v.x); o.y=f2bf(v.y); o.z=f2bf(v.z); o.w=f2bf(v.w);
  *reinterpret_cast<ushort4*>(dst + blockIdx.z * dst_estride
                              + (size_t)row * HD + dcol + c) = o;
}

// ---------------- GEMM 1: x @ W1(interleaved gate/up) + silu*mul -> inter ----------
// 256 thr = 4 waves (2x2). Tile M=128 tokens, N=128 W1-rows (=64 inter cols), BK=32.
// Ring-3 LDS (48 KB): buf = {A 8KB, B 8KB}. Fragment-ordered regions:
// frag f (rows 16f..16f+15) at f*1024B; lane l covers row 16f+(l&15), k (l>>4)*8.
__global__ __launch_bounds__(256, 3) void k_gu(
    const unsigned short* __restrict__ xbf,
    const unsigned short* __restrict__ W1,   // [8][2048][1024]
    const int* __restrict__ perm, const int* __restrict__ cnt, const int* __restrict__ off,
    unsigned short* __restrict__ inter) {
  const int e = blockIdx.z;
  const int ce = cnt[e];
  const int m0 = blockIdx.y * 128;
  if (m0 >= ce) return;
  const int n0 = blockIdx.x * 128;
  const int oe = off[e];
  __shared__ __attribute__((aligned(16))) unsigned short sm[24576];  // 48 KB
  const int tid = threadIdx.x;
  const int lane = tid & 63;
  const int wv = tid >> 6;
  const int wm = wv >> 1, wn = wv & 1;

  // staging source: lane covers row wv*16+(lane&15) (+64 for 2nd call), k ((lane>>4)&3)*8
  const int srw = wv * 16 + (lane & 15);
  const int srk = ((lane >> 4) & 3) * 8;
  int ia = m0 + srw;        if (ia > ce - 1) ia = ce - 1;
  int ib = m0 + 64 + srw;   if (ib > ce - 1) ib = ce - 1;
  const unsigned short* pA0 = xbf + (size_t)perm[oe + ia] * HD + srk;
  const unsigned short* pA1 = xbf + (size_t)perm[oe + ib] * HD + srk;
  const unsigned short* pB0 = W1 + ((size_t)e << 21) + (size_t)(n0 + srw) * HD + srk;
  const unsigned short* pB1 = W1 + ((size_t)e << 21) + (size_t)(n0 + 64 + srw) * HD + srk;

  f32x4 acc[4][4];
#pragma unroll
  for (int mi = 0; mi < 4; mi++)
#pragma unroll
    for (int ni = 0; ni < 4; ni++) acc[mi][ni] = (f32x4){0.f, 0.f, 0.f, 0.f};

  auto STAGE = [&](int b, int kt) {
    const int ko = kt * 32;
    unsigned short* la = sm + b * 8192 + wv * 512;          // wave-uniform dests
    unsigned short* lb = sm + b * 8192 + 4096 + wv * 512;
    gld16(pA0 + ko, la);
    gld16(pA1 + ko, la + 2048);
    gld16(pB0 + ko, lb);
    gld16(pB1 + ko, lb + 2048);
  };
  auto COMPUTE = [&](int b) {
    const unsigned short* A = sm + b * 8192;
    const unsigned short* B = A + 4096;
    bf16x8 a[4], bb[4];
#pragma unroll
    for (int mi = 0; mi < 4; mi++)
      a[mi] = *reinterpret_cast<const bf16x8*>(A + (wm * 4 + mi) * 512 + lane * 8);
#pragma unroll
    for (int ni = 0; ni < 4; ni++)
      bb[ni] = *reinterpret_cast<const bf16x8*>(B + (wn * 4 + ni) * 512 + lane * 8);
    __builtin_amdgcn_s_setprio(1);
#pragma unroll
    for (int mi = 0; mi < 4; mi++)
#pragma unroll
      for (int ni = 0; ni < 4; ni++)
        acc[mi][ni] = __builtin_amdgcn_mfma_f32_16x16x32_bf16(a[mi], bb[ni], acc[mi][ni], 0, 0, 0);
    __builtin_amdgcn_s_setprio(0);
  };

  STAGE(0, 0); STAGE(1, 1);
  int bn = 2, bc = 0;
#pragma unroll 1
  for (int kt = 0; kt < 30; kt++) {
    STAGE(bn, kt + 2);
    asm volatile("s_waitcnt vmcnt(8)" ::: "memory");   // tile kt landed (2 iters old)
    BAR();
    COMPUTE(bc);
    BAR();                                             // reads done: buffer reusable
    bn = bn == 2 ? 0 : bn + 1;
    bc = bc == 2 ? 0 : bc + 1;
  }
  asm volatile("s_waitcnt vmcnt(4)" ::: "memory"); BAR(); COMPUTE(0); BAR();
  asm volatile("s_waitcnt vmcnt(0)" ::: "memory"); BAR(); COMPUTE(1);

  // epilogue: n-frags alternate (gate, up) per 16; pair in-register.
  // active tile => all 128 rows < cep (128-aligned), no row guard needed.
  const int colbase = (n0 + wn * 64) >> 1;
#pragma unroll
  for (int mi = 0; mi < 4; mi++)
#pragma unroll
    for (int p = 0; p < 2; p++)
#pragma unroll
      for (int r = 0; r < 4; r++) {
        int m = wm * 64 + mi * 16 + (lane >> 4) * 4 + r;
        float g = acc[mi][2 * p][r];
        float u = acc[mi][2 * p + 1][r];
        float sv = g / (1.f + __expf(-g)) * u;
        inter[(size_t)(oe + m0 + m) * HD + colbase + p * 16 + (lane & 15)] = f2bf(sv);
      }
}

// ---------------- GEMM 2: inter @ Dcat -> out (scatter rows via perm) ----------------
// Same ring-3 counted-vmcnt skeleton. Tile M=128, N=128 out cols, BK=32.
__global__ __launch_bounds__(256, 3) void k_down(
    const unsigned short* __restrict__ inter,
    const unsigned short* __restrict__ Dt,   // [8][1024][1024] B^T
    const int* __restrict__ perm, const int* __restrict__ cnt, const int* __restrict__ off,
    float* __restrict__ out) {
  const int e = blockIdx.z;
  const int ce = cnt[e];
  const int m0 = blockIdx.y * 128;
  if (m0 >= ce) return;
  const int n0 = blockIdx.x * 128;
  const int oe = off[e];
  __shared__ __attribute__((aligned(16))) unsigned short sm[24576];
  const int tid = threadIdx.x;
  const int lane = tid & 63;
  const int wv = tid >> 6;
  const int wm = wv >> 1, wn = wv & 1;

  const int srw = wv * 16 + (lane & 15);
  const int srk = ((lane >> 4) & 3) * 8;
  const unsigned short* pA0 = inter + (size_t)(oe + m0 + srw) * HD + srk;       // rows < cep valid
  const unsigned short* pA1 = inter + (size_t)(oe + m0 + 64 + srw) * HD + srk;
  const unsigned short* pB0 = Dt + ((size_t)e << 20) + (size_t)(n0 + srw) * HD + srk;
  const unsigned short* pB1 = Dt + ((size_t)e << 20) + (size_t)(n0 + 64 + srw) * HD + srk;

  f32x4 acc[4][4];
#pragma unroll
  for (int mi = 0; mi < 4; mi++)
#pragma unroll
    for (int ni = 0; ni < 4; ni++) acc[mi][ni] = (f32x4){0.f, 0.f, 0.f, 0.f};

  auto STAGE = [&](int b, int kt) {
    const int ko = kt * 32;
    unsigned short* la = sm + b * 8192 + wv * 512;
    unsigned short* lb = sm + b * 8192 + 4096 + wv * 512;
    gld16(pA0 + ko, la);
    gld16(pA1 + ko, la + 2048);
    gld16(pB0 + ko, lb);
    gld16(pB1 + ko, lb + 2048);
  };
  auto COMPUTE = [&](int b) {
    const unsigned short* A = sm + b * 8192;
    const unsigned short* B = A + 4096;
    bf16x8 a[4], bb[4];
#pragma unroll
    for (int mi = 0; mi < 4; mi++)
      a[mi] = *reinterpret_cast<const bf16x8*>(A + (wm * 4 + mi) * 512 + lane * 8);
#pragma unroll
    for (int ni = 0; ni < 4; ni++)
      bb[ni] = *reinterpret_cast<const bf16x8*>(B + (wn * 4 + ni) * 512 + lane * 8);
    __builtin_amdgcn_s_setprio(1);
#pragma unroll
    for (int mi = 0; mi < 4; mi++)
#pragma unroll
      for (int ni = 0; ni < 4; ni++)
        acc[mi][ni] = __builtin_amdgcn_mfma_f32_16x16x32_bf16(a[mi], bb[ni], acc[mi][ni], 0, 0, 0);
    __builtin_amdgcn_s_setprio(0);
  };

  STAGE(0, 0); STAGE(1, 1);
  int bn = 2, bc = 0;
#pragma unroll 1
  for (int kt = 0; kt < 30; kt++) {
    STAGE(bn, kt + 2);
    asm volatile("s_waitcnt vmcnt(8)" ::: "memory");
    BAR();
    COMPUTE(bc);
    BAR();
    bn = bn == 2 ? 0 : bn + 1;
    bc = bc == 2 ? 0 : bc + 1;
  }
  asm volatile("s_waitcnt vmcnt(4)" ::: "memory"); BAR(); COMPUTE(0); BAR();
  asm volatile("s_waitcnt vmcnt(0)" ::: "memory"); BAR(); COMPUTE(1);

#pragma unroll
  for (int mi = 0; mi < 4; mi++)
#pragma unroll
    for (int r = 0; r < 4; r++) {
      int m = wm * 64 + mi * 16 + (lane >> 4) * 4 + r;
      int gm = m0 + m;
      if (gm < ce) {                      // only real tokens scatter
        int t = perm[oe + gm];
#pragma unroll
        for (int ni = 0; ni < 4; ni++)
          out[(size_t)t * HD + n0 + wn * 64 + ni * 16 + (lane & 15)] = acc[mi][ni][r];
      }
    }
}

// ---------------- naive fp32 fallback (only if ws too small) ----------------
__global__ __launch_bounds__(256) void k_naive(
    const float* __restrict__ x, const int* __restrict__ ids,
    const float* __restrict__ gw, const float* __restrict__ uw, const float* __restrict__ dw,
    const float* __restrict__ sgw, const float* __restrict__ suw, const float* __restrict__ sdw,
    float* __restrict__ out) {
  const int t = blockIdx.x;
  const int tid = threadIdx.x;
  __shared__ float sx[1024];
  __shared__ float si[1024];
  for (int i = tid; i < 1024; i += 256) sx[i] = x[(size_t)t * 1024 + i];
  const int e = expert_of(ids[t]);
  __syncthreads();
  const float* gwe = gw + (size_t)e * 1024 * 512;
  const float* uwe = uw + (size_t)e * 1024 * 512;
  for (int j = tid; j < 512; j += 256) {
    float g = 0, u = 0, sg = 0, su = 0;
    for (int k = 0; k < 1024; k++) {
      float xv = sx[k];
      g += xv * gwe[(size_t)k * 512 + j];
      u += xv * uwe[(size_t)k * 512 + j];
      sg += xv * sgw[(size_t)j * 1024 + k];
      su += xv * suw[(size_t)j * 1024 + k];
    }
    si[j] = g / (1.f + __expf(-g)) * u;
    si[512 + j] = sg / (1.f + __expf(-sg)) * su;
  }
  __syncthreads();
  const float* dwe = dw + (size_t)e * 512 * 1024;
  for (int n = tid; n < 1024; n += 256) {
    float a = 0;
    for (int k = 0; k < 512; k++)
      a += si[k] * dwe[(size_t)k * 1024 + n] + si[512 + k] * sdw[(size_t)n * 512 + k];
    out[(size_t)t * 1024 + n] = a;
  }
}

extern "C" void kernel_launch(void* const* d_in, const int* in_sizes, int n_in,
                              void* d_out, int out_size, void* d_ws, size_t ws_size,
                              hipStream_t stream) {
  const float* x = (const float*)d_in[0];
  const int* ids = (const int*)d_in[1];          // harness passes integers as int32
  const float* gw = (const float*)d_in[2];
  const float* uw = (const float*)d_in[3];
  const float* dw = (const float*)d_in[4];
  const float* sgw = (const float*)d_in[5];
  const float* suw = (const float*)d_in[6];
  const float* sdw = (const float*)d_in[7];
  float* out = (float*)d_out;

  const size_t REQ = 186908672ull;
  if (ws_size < REQ) {
    k_naive<<<N_TOK, 256, 0, stream>>>(x, ids, gw, uw, dw, sgw, suw, sdw, out);
    return;
  }

  char* ws = (char*)d_ws;
  int* ctrl = (int*)ws;                                   // cnt[8] | cursor[8] | off[9]
  int* perm = (int*)(ws + 1024);                          // 33792 ints
  unsigned short* xbf = (unsigned short*)(ws + 262144);   // [32768][1024]
  unsigned short* W1 = (unsigned short*)(ws + 67371008ull);   // [8][2048][1024] interleaved
  unsigned short* Dt = (unsigned short*)(ws + 100925440ull);  // [8][1024][1024]
  unsigned short* inter = (unsigned short*)(ws + 117702656ull); // [33792][1024]

  k_zero<<<1, 64, 0, stream>>>(ctrl);
  k_count<<<128, 256, 0, stream>>>(ids, ctrl);
  k_scan<<<1, 64, 0, stream>>>(ctrl, ctrl + 16);
  k_fill<<<128, 256, 0, stream>>>(ids, ctrl + 8, ctrl + 16, perm);
  k_cvt_x<<<16384, 256, 0, stream>>>(x, xbf);
  // routed weights: gate/up [1024][512] -> W1 interleaved rows; down [512][1024] -> Dt plain
  k_transpose_cvt<<<dim3(16, 32, 8), 256, 0, stream>>>(gw, W1, 512, 1,
                                                       (size_t)1024 * 512, (size_t)1 << 21);
  k_transpose_cvt<<<dim3(16, 32, 8), 256, 0, stream>>>(uw, W1, 512, 2,
                                                       (size_t)1024 * 512, (size_t)1 << 21);
  k_transpose_cvt<<<dim3(32, 16, 8), 256, 0, stream>>>(dw, Dt, 1024, 0,
                                                       (size_t)512 * 1024, (size_t)1 << 20);
  // shared weights appended (replicated per expert)
  k_copy_cvt<<<dim3(512, 1, 8), 256, 0, stream>>>(sgw, W1, 1024, 1, 0, (size_t)1 << 21);
  k_copy_cvt<<<dim3(512, 1, 8), 256, 0, stream>>>(suw, W1, 1024, 2, 0, (size_t)1 << 21);
  k_copy_cvt<<<dim3(512, 1, 8), 256, 0, stream>>>(sdw, Dt, 512, 0, 512, (size_t)1 << 20);
  // grouped GEMMs (128^2 tiles, ring-3 counted-vmcnt, ~3 blocks/CU)
  k_gu<<<dim3(16, 256, 8), 256, 0, stream>>>(xbf, W1, perm, ctrl, ctrl + 16, inter);
  k_down<<<dim3(8, 256, 8), 256, 0, stream>>>(inter, Dt, perm, ctrl, ctrl + 16, out);
}

// Round 13
// 368.696 us; speedup vs baseline: 1.3146x; 1.3146x over previous
//
#include <hip/hip_runtime.h>
#include <hip/hip_bf16.h>

// TokenRoutedMLP: N=32768 tokens, H=1024, 8 routed experts (id%8) + shared expert.
// Grouped bf16 MFMA GEMMs; shared expert folded via concat weights; gate/up
// interleaved by 16 cols in W1 so silu pairing is in-register.
// GEMM: R6-exact 2ph dbuf structure (best measured: 193 us, 735 TF) —
// 128x128 tile, BK=32, 4 waves, 32 KiB LDS, STAGE(t+1)||COMPUTE(t)->syncthreads,
// ~3+ blocks/CU so the barrier drain is hidden by other resident blocks.
// NEW vs R6: compacted grid (no dead blocks; tile->expert via ybase table) and
// fused weight-prep kernel (13 -> 8 launches).
// global_load_lds: LDS dest wave-uniform base + lane*16B (m104/m108).

#define N_TOK 32768
#define HD 1024
#define NE 8
#define MAXYT 264   // ceil((32768 + 8*127)/128)

typedef __attribute__((ext_vector_type(8))) short bf16x8;
typedef __attribute__((ext_vector_type(8))) unsigned short u16x8;
typedef __attribute__((ext_vector_type(4))) float f32x4;

__device__ __forceinline__ unsigned short f2bf(float f) {
  unsigned int x = __float_as_uint(f);
  x += 0x7fffu + ((x >> 16) & 1u);   // RTNE
  return (unsigned short)(x >> 16);
}

__device__ __forceinline__ void gld16(const unsigned short* g, unsigned short* l) {
  __builtin_amdgcn_global_load_lds(
      (const __attribute__((address_space(1))) unsigned int*)g,
      (__attribute__((address_space(3))) unsigned int*)l,
      16, 0, 0);
}

__device__ __forceinline__ int expert_of(int id) {
  int v = id < 0 ? 0 : (id > 99999 ? 99999 : id);
  return v & 7;
}

// ---------------- routing (LDS-histogram; 8 global atomics per block) ----------
__global__ void k_zero(int* ctrl) {
  if (threadIdx.x < 16) ctrl[threadIdx.x] = 0;   // cnt[8], cursor[8]
}

__global__ void k_count(const int* __restrict__ ids, int* __restrict__ cnt) {
  __shared__ int l[NE];
  if (threadIdx.x < NE) l[threadIdx.x] = 0;
  __syncthreads();
  int t = blockIdx.x * 256 + threadIdx.x;
  atomicAdd(&l[expert_of(ids[t])], 1);
  __syncthreads();
  if (threadIdx.x < NE) atomicAdd(&cnt[threadIdx.x], l[threadIdx.x]);
}

// off[0..8] = 128-aligned segment starts; off[9..17] = ybase (tile index starts)
__global__ void k_scan(const int* __restrict__ cnt, int* __restrict__ off) {
  if (threadIdx.x == 0 && blockIdx.x == 0) {
    int a = 0;
    for (int e = 0; e < NE; e++) { off[e] = a; a += (cnt[e] + 127) & ~127; }
    off[NE] = a;
    for (int e = 0; e <= NE; e++) off[9 + e] = off[e] >> 7;
  }
}

__global__ void k_fill(const int* __restrict__ ids, int* __restrict__ cursor,
                       const int* __restrict__ off, int* __restrict__ perm) {
  __shared__ int lcnt[NE], lbase[NE];
  if (threadIdx.x < NE) lcnt[threadIdx.x] = 0;
  __syncthreads();
  int t = blockIdx.x * 256 + threadIdx.x;
  int e = expert_of(ids[t]);
  int r = atomicAdd(&lcnt[e], 1);          // rank within block
  __syncthreads();
  if (threadIdx.x < NE)
    lbase[threadIdx.x] = atomicAdd(&cursor[threadIdx.x], lcnt[threadIdx.x]);
  __syncthreads();
  perm[off[e] + lbase[e] + r] = t;
}

// ---------------- conversions / weight build ----------------
__global__ void k_cvt_x(const float* __restrict__ src, unsigned short* __restrict__ dst) {
  size_t i = ((size_t)blockIdx.x * 256 + threadIdx.x) * 8;
  float4 a = *reinterpret_cast<const float4*>(src + i);
  float4 b = *reinterpret_cast<const float4*>(src + i + 4);
  u16x8 o;
  o[0]=f2bf(a.x); o[1]=f2bf(a.y); o[2]=f2bf(a.z); o[3]=f2bf(a.w);
  o[4]=f2bf(b.x); o[5]=f2bf(b.y); o[6]=f2bf(b.z); o[7]=f2bf(b.w);
  *reinterpret_cast<u16x8*>(dst + i) = o;
}

// row remap: mode 0 plain; mode 1 gate-interleave; mode 2 up-interleave
__device__ __forceinline__ int rowmap(int c, int mode) {
  if (mode == 0) return c;
  return ((c >> 4) << 5) + (c & 15) + (mode == 2 ? 16 : 0);
}

// Fused weight prep. 6 sections x 4096 blocks:
//  0: gw  [1024][512]  -T-> W1 rows rowmap(c,1)        3: sgw [512][1024] copy-> W1 row 1024+rowmap(r,1)
//  1: uw  [1024][512]  -T-> W1 rows rowmap(c,2)        4: suw [512][1024] copy-> W1 row 1024+rowmap(r,2)
//  2: dw  [512][1024]  -T-> Dt rows c                  5: sdw [1024][512] copy-> Dt row r, col 512+c
__global__ void k_prep_w(const float* __restrict__ gw, const float* __restrict__ uw,
                         const float* __restrict__ dw, const float* __restrict__ sgw,
                         const float* __restrict__ suw, const float* __restrict__ sdw,
                         unsigned short* __restrict__ W1, unsigned short* __restrict__ Dt) {
  const int sec = blockIdx.x >> 12;
  const int idx = blockIdx.x & 4095;
  const int t = threadIdx.x;
  const int e = idx >> 9;
  __shared__ __attribute__((aligned(16))) float tile[32][33];
  if (sec < 3) {
    const float* src; unsigned short* dst; int C, mode, bx, by;
    size_t se, de;
    if (sec == 0)      { src = gw; dst = W1; C = 512;  mode = 1; se = (size_t)1024*512; de = (size_t)1<<21; bx = idx & 15; by = (idx >> 4) & 31; }
    else if (sec == 1) { src = uw; dst = W1; C = 512;  mode = 2; se = (size_t)1024*512; de = (size_t)1<<21; bx = idx & 15; by = (idx >> 4) & 31; }
    else               { src = dw; dst = Dt; C = 1024; mode = 0; se = (size_t)512*1024; de = (size_t)1<<20; bx = idx & 31; by = (idx >> 5) & 15; }
    src += e * se; dst += e * de;
    int r0 = by * 32, c0 = bx * 32;
    int row = t >> 3, c4 = (t & 7) * 4;
    float4 v = *reinterpret_cast<const float4*>(src + (size_t)(r0 + row) * C + c0 + c4);
    tile[row][c4+0] = v.x; tile[row][c4+1] = v.y; tile[row][c4+2] = v.z; tile[row][c4+3] = v.w;
    __syncthreads();
    ushort4 o;
    o.x = f2bf(tile[c4+0][row]); o.y = f2bf(tile[c4+1][row]);
    o.z = f2bf(tile[c4+2][row]); o.w = f2bf(tile[c4+3][row]);
    int orow = rowmap(c0 + row, mode);
    *reinterpret_cast<ushort4*>(dst + (size_t)orow * HD + r0 + c4) = o;
  } else {
    const float* src; unsigned short* dst; int mode, dcol, cols;
    size_t de;
    if (sec == 3)      { src = sgw; dst = W1; mode = 1; dcol = 0;   cols = 1024; de = (size_t)1<<21; }
    else if (sec == 4) { src = suw; dst = W1; mode = 2; dcol = 0;   cols = 1024; de = (size_t)1<<21; }
    else               { src = sdw; dst = Dt; mode = 0; dcol = 512; cols = 512;  de = (size_t)1<<20; }
    int bx = idx & 511;
    size_t i = ((size_t)bx * 256 + t) * 4;
    int r = (int)(i / cols), c = (int)(i % cols);
    int row = (mode == 0) ? r : (1024 + rowmap(r, mode));
    float4 v = *reinterpret_cast<const float4*>(src + i);
    ushort4 o; o.x=f2bf(v.x); o.y=f2bf(v.y); o.z=f2bf(v.z); o.w=f2bf(v.w);
    *reinterpret_cast<ushort4*>(dst + e * de + (size_t)row * HD + dcol + c) = o;
  }
}

// tile -> (expert, m0) from ybase table (off+9)
__device__ __forceinline__ int tile_expert(const int* yb, int yt) {
  int e = 0;
#pragma unroll
  for (int i = 1; i < NE; i++) if (yt >= yb[i]) e = i;
  return e;
}

// ---------------- GEMM 1: x @ W1(interleaved gate/up) + silu*mul -> inter ----------
// 256 thr = 4 waves (2x2). Tile M=128 tokens, N=128 W1-rows (=64 inter cols), BK=32.
// R6-exact loop: STAGE(t+1) || COMPUTE(t) -> __syncthreads.
__global__ __launch_bounds__(256, 3) void k_gu(
    const unsigned short* __restrict__ xbf,
    const unsigned short* __restrict__ W1,   // [8][2048][1024]
    const int* __restrict__ perm, const int* __restrict__ cnt, const int* __restrict__ off,
    unsigned short* __restrict__ inter) {
  const int yt = blockIdx.y;
  const int e = tile_expert(off + 9, yt);
  const int ce = cnt[e];
  const int m0 = (yt - (off + 9)[e]) * 128;
  if (m0 >= ce) return;                      // trailing pad tiles only
  const int n0 = blockIdx.x * 128;
  const int oe = off[e];
  __shared__ __attribute__((aligned(16))) unsigned short smA[2 * 128 * 32];  // 16 KB
  __shared__ __attribute__((aligned(16))) unsigned short smB[2 * 128 * 32];  // 16 KB
  const int tid = threadIdx.x;
  const int lane = tid & 63;
  const int wv = tid >> 6;
  const int wm = wv >> 1, wn = wv & 1;

  // staging: thread t covers row (s*64 + t/4), k-col (t%4)*8 (16B)
  const int srow = tid >> 2;
  const int skol = (tid & 3) * 8;
  const unsigned short* sa[2];
  const unsigned short* sb[2];
#pragma unroll
  for (int s = 0; s < 2; s++) {
    int i = m0 + s * 64 + srow;
    if (i > ce - 1) i = ce - 1;
    int tok = perm[oe + i];
    sa[s] = xbf + (size_t)tok * HD + skol;
    sb[s] = W1 + ((size_t)e << 21) + (size_t)(n0 + s * 64 + srow) * HD + skol;
  }

  f32x4 acc[4][4];
#pragma unroll
  for (int mi = 0; mi < 4; mi++)
#pragma unroll
    for (int ni = 0; ni < 4; ni++) acc[mi][ni] = (f32x4){0.f, 0.f, 0.f, 0.f};

  auto STAGE = [&](int b, int kt) {
    const int ko = kt * 32;
#pragma unroll
    for (int s = 0; s < 2; s++) {
      gld16(sa[s] + ko, smA + b * 4096 + s * 2048 + wv * 512);  // wave-uniform dest
      gld16(sb[s] + ko, smB + b * 4096 + s * 2048 + wv * 512);
    }
  };
  auto COMPUTE = [&](int b) {
    const unsigned short* A = smA + b * 4096;
    const unsigned short* B = smB + b * 4096;
    bf16x8 a[4], bb[4];
#pragma unroll
    for (int mi = 0; mi < 4; mi++)
      a[mi] = *reinterpret_cast<const bf16x8*>(A + (wm * 64 + mi * 16 + (lane & 15)) * 32 + (lane >> 4) * 8);
#pragma unroll
    for (int ni = 0; ni < 4; ni++)
      bb[ni] = *reinterpret_cast<const bf16x8*>(B + (wn * 64 + ni * 16 + (lane & 15)) * 32 + (lane >> 4) * 8);
#pragma unroll
    for (int mi = 0; mi < 4; mi++)
#pragma unroll
      for (int ni = 0; ni < 4; ni++)
        acc[mi][ni] = __builtin_amdgcn_mfma_f32_16x16x32_bf16(a[mi], bb[ni], acc[mi][ni], 0, 0, 0);
  };

  STAGE(0, 0);
  __syncthreads();
  int cur = 0;
#pragma unroll 1
  for (int kt = 0; kt < 31; kt++) {
    STAGE(cur ^ 1, kt + 1);   // next tile's loads fly during this tile's MFMA
    COMPUTE(cur);
    __syncthreads();          // drains vmcnt(0); other resident blocks hide it
    cur ^= 1;
  }
  COMPUTE(cur);

  // epilogue: n-frags alternate (gate, up) per 16; pair in-register.
  // active tile => all 128 rows < cep (cep 128-aligned), no row guard needed.
  const int colbase = (n0 + wn * 64) >> 1;
#pragma unroll
  for (int mi = 0; mi < 4; mi++)
#pragma unroll
    for (int p = 0; p < 2; p++)
#pragma unroll
      for (int r = 0; r < 4; r++) {
        int m = wm * 64 + mi * 16 + (lane >> 4) * 4 + r;
        float g = acc[mi][2 * p][r];
        float u = acc[mi][2 * p + 1][r];
        float sv = g / (1.f + __expf(-g)) * u;
        inter[(size_t)(oe + m0 + m) * HD + colbase + p * 16 + (lane & 15)] = f2bf(sv);
      }
}

// ---------------- GEMM 2: inter @ Dcat -> out (scatter rows via perm) ----------------
// Same R6-exact skeleton. Tile M=128, N=128 out cols, BK=32.
__global__ __launch_bounds__(256, 3) void k_down(
    const unsigned short* __restrict__ inter,
    const unsigned short* __restrict__ Dt,   // [8][1024][1024] B^T
    const int* __restrict__ perm, const int* __restrict__ cnt, const int* __restrict__ off,
    float* __restrict__ out) {
  const int yt = blockIdx.y;
  const int e = tile_expert(off + 9, yt);
  const int ce = cnt[e];
  const int m0 = (yt - (off + 9)[e]) * 128;
  if (m0 >= ce) return;
  const int n0 = blockIdx.x * 128;
  const int oe = off[e];
  __shared__ __attribute__((aligned(16))) unsigned short smA[2 * 128 * 32];
  __shared__ __attribute__((aligned(16))) unsigned short smB[2 * 128 * 32];
  const int tid = threadIdx.x;
  const int lane = tid & 63;
  const int wv = tid >> 6;
  const int wm = wv >> 1, wn = wv & 1;

  const int srow = tid >> 2;
  const int skol = (tid & 3) * 8;
  const unsigned short* sa[2];
  const unsigned short* sb[2];
#pragma unroll
  for (int s = 0; s < 2; s++) {
    sa[s] = inter + (size_t)(oe + m0 + s * 64 + srow) * HD + skol;  // rows < cep valid
    sb[s] = Dt + ((size_t)e << 20) + (size_t)(n0 + s * 64 + srow) * HD + skol;
  }

  f32x4 acc[4][4];
#pragma unroll
  for (int mi = 0; mi < 4; mi++)
#pragma unroll
    for (int ni = 0; ni < 4; ni++) acc[mi][ni] = (f32x4){0.f, 0.f, 0.f, 0.f};

  auto STAGE = [&](int b, int kt) {
    const int ko = kt * 32;
#pragma unroll
    for (int s = 0; s < 2; s++) {
      gld16(sa[s] + ko, smA + b * 4096 + s * 2048 + wv * 512);
      gld16(sb[s] + ko, smB + b * 4096 + s * 2048 + wv * 512);
    }
  };
  auto COMPUTE = [&](int b) {
    const unsigned short* A = smA + b * 4096;
    const unsigned short* B = smB + b * 4096;
    bf16x8 a[4], bb[4];
#pragma unroll
    for (int mi = 0; mi < 4; mi++)
      a[mi] = *reinterpret_cast<const bf16x8*>(A + (wm * 64 + mi * 16 + (lane & 15)) * 32 + (lane >> 4) * 8);
#pragma unroll
    for (int ni = 0; ni < 4; ni++)
      bb[ni] = *reinterpret_cast<const bf16x8*>(B + (wn * 64 + ni * 16 + (lane & 15)) * 32 + (lane >> 4) * 8);
#pragma unroll
    for (int mi = 0; mi < 4; mi++)
#pragma unroll
      for (int ni = 0; ni < 4; ni++)
        acc[mi][ni] = __builtin_amdgcn_mfma_f32_16x16x32_bf16(a[mi], bb[ni], acc[mi][ni], 0, 0, 0);
  };

  STAGE(0, 0);
  __syncthreads();
  int cur = 0;
#pragma unroll 1
  for (int kt = 0; kt < 31; kt++) {
    STAGE(cur ^ 1, kt + 1);
    COMPUTE(cur);
    __syncthreads();
    cur ^= 1;
  }
  COMPUTE(cur);

#pragma unroll
  for (int mi = 0; mi < 4; mi++)
#pragma unroll
    for (int r = 0; r < 4; r++) {
      int m = wm * 64 + mi * 16 + (lane >> 4) * 4 + r;
      int gm = m0 + m;
      if (gm < ce) {                      // only real tokens scatter
        int t = perm[oe + gm];
#pragma unroll
        for (int ni = 0; ni < 4; ni++)
          out[(size_t)t * HD + n0 + wn * 64 + ni * 16 + (lane & 15)] = acc[mi][ni][r];
      }
    }
}

// ---------------- naive fp32 fallback (only if ws too small) ----------------
__global__ __launch_bounds__(256) void k_naive(
    const float* __restrict__ x, const int* __restrict__ ids,
    const float* __restrict__ gw, const float* __restrict__ uw, const float* __restrict__ dw,
    const float* __restrict__ sgw, const float* __restrict__ suw, const float* __restrict__ sdw,
    float* __restrict__ out) {
  const int t = blockIdx.x;
  const int tid = threadIdx.x;
  __shared__ float sx[1024];
  __shared__ float si[1024];
  for (int i = tid; i < 1024; i += 256) sx[i] = x[(size_t)t * 1024 + i];
  const int e = expert_of(ids[t]);
  __syncthreads();
  const float* gwe = gw + (size_t)e * 1024 * 512;
  const float* uwe = uw + (size_t)e * 1024 * 512;
  for (int j = tid; j < 512; j += 256) {
    float g = 0, u = 0, sg = 0, su = 0;
    for (int k = 0; k < 1024; k++) {
      float xv = sx[k];
      g += xv * gwe[(size_t)k * 512 + j];
      u += xv * uwe[(size_t)k * 512 + j];
      sg += xv * sgw[(size_t)j * 1024 + k];
      su += xv * suw[(size_t)j * 1024 + k];
    }
    si[j] = g / (1.f + __expf(-g)) * u;
    si[512 + j] = sg / (1.f + __expf(-sg)) * su;
  }
  __syncthreads();
  const float* dwe = dw + (size_t)e * 512 * 1024;
  for (int n = tid; n < 1024; n += 256) {
    float a = 0;
    for (int k = 0; k < 512; k++)
      a += si[k] * dwe[(size_t)k * 1024 + n] + si[512 + k] * sdw[(size_t)n * 512 + k];
    out[(size_t)t * 1024 + n] = a;
  }
}

extern "C" void kernel_launch(void* const* d_in, const int* in_sizes, int n_in,
                              void* d_out, int out_size, void* d_ws, size_t ws_size,
                              hipStream_t stream) {
  const float* x = (const float*)d_in[0];
  const int* ids = (const int*)d_in[1];          // harness passes integers as int32
  const float* gw = (const float*)d_in[2];
  const float* uw = (const float*)d_in[3];
  const float* dw = (const float*)d_in[4];
  const float* sgw = (const float*)d_in[5];
  const float* suw = (const float*)d_in[6];
  const float* sdw = (const float*)d_in[7];
  float* out = (float*)d_out;

  const size_t REQ = 186908672ull;
  if (ws_size < REQ) {
    k_naive<<<N_TOK, 256, 0, stream>>>(x, ids, gw, uw, dw, sgw, suw, sdw, out);
    return;
  }

  char* ws = (char*)d_ws;
  int* ctrl = (int*)ws;                                   // cnt[8]|cursor[8]|off[9]|ybase[9]
  int* perm = (int*)(ws + 1024);                          // 33792 ints
  unsigned short* xbf = (unsigned short*)(ws + 262144);   // [32768][1024]
  unsigned short* W1 = (unsigned short*)(ws + 67371008ull);   // [8][2048][1024] interleaved
  unsigned short* Dt = (unsigned short*)(ws + 100925440ull);  // [8][1024][1024]
  unsigned short* inter = (unsigned short*)(ws + 117702656ull); // [33792][1024]

  k_zero<<<1, 64, 0, stream>>>(ctrl);
  k_count<<<128, 256, 0, stream>>>(ids, ctrl);
  k_scan<<<1, 64, 0, stream>>>(ctrl, ctrl + 16);
  k_fill<<<128, 256, 0, stream>>>(ids, ctrl + 8, ctrl + 16, perm);
  k_cvt_x<<<16384, 256, 0, stream>>>(x, xbf);
  k_prep_w<<<6 * 4096, 256, 0, stream>>>(gw, uw, dw, sgw, suw, sdw, W1, Dt);
  // grouped GEMMs (128^2 tiles, compacted grid: only real tiles dispatched)
  k_gu<<<dim3(16, MAXYT), 256, 0, stream>>>(xbf, W1, perm, ctrl, ctrl + 16, inter);
  k_down<<<dim3(8, MAXYT), 256, 0, stream>>>(inter, Dt, perm, ctrl, ctrl + 16, out);
}